// Round 12
// baseline (56.352 us; speedup 1.0000x reference)
//
#include <hip/hip_runtime.h>
#include <hip/hip_fp16.h>

// Depthwise 3D Gaussian conv (1,3,160,160,160) fp32, K=25, radius=12.
// Separable -> three 1-D passes, fp16 intermediates.
// Round 12: conv_w rebuilt row-major (linear float4 stage, sliding window
// along the row, direct coalesced half2 stores, 12 KB LDS -> 8 blocks/CU).
// conv_h / conv_d unchanged from r11 (full-w tiles, linear uint4 stage).

#define NV 160
constexpr int KS    = 25;
constexpr int RAD   = 12;
constexpr int PLANE = NV * NV;        // 25600
constexpr int VOL   = NV * NV * NV;   // 4,096,000
constexpr int TOT   = 3 * VOL;        // 12,288,000

// W-pass geometry (row-major)
constexpr int WHR   = 16;             // h rows per block
constexpr int WPIT  = 189;            // floats per row (184 used + 5 pad, odd)
constexpr int OPT   = 10;
constexpr int WIN   = OPT + KS - 1;   // 34

// H/D-pass geometry (r11 full-w tiles)
constexpr int HC2   = 80;             // outputs per block along conv axis
constexpr int TR    = HC2 + 2 * RAD;  // 104 tile rows
constexpr int TP2   = 84;             // half2 pitch
constexpr int NTASK = TR * 20;        // 2080 stage tasks (16B each)

__device__ __forceinline__ void pk(float2& a, float2 g, float2 v) {
    asm("v_pk_fma_f32 %0, %1, %2, %0" : "+v"(a) : "v"(g), "v"(v));
}

// Recover g1[t] from k3: g1[t] = g3[t,12,12] / cbrt(g3[12,12,12])^2 (exact).
__device__ __forceinline__ void load_g(const float* __restrict__ k3, float* g) {
    float c   = k3[12 * 625 + 312];          // g1[12]^3
    float g12 = cbrtf(c);
    float inv = 1.0f / (g12 * g12);
#pragma unroll
    for (int t = 0; t < KS; ++t) g[t] = k3[t * 625 + 312] * inv;
}

// ---------------- W pass: f32 in -> f16 out (row-major tile) ----------------
__global__ __launch_bounds__(256) void conv_w(const float* __restrict__ in,
                                              __half* __restrict__ out,
                                              const float* __restrict__ k3) {
    __shared__ float X[WHR][WPIT];           // 16*189*4 = 12096 B
    float g[KS];
    load_g(k3, g);

    int tid = threadIdx.x;
    int b   = blockIdx.x;
    int hc  = b % 10;
    int cd  = b / 10;              // c*160 + d
    int h0  = hc * WHR;
    const float* base = in + (size_t)cd * PLANE + (size_t)h0 * NV;

    // zero the w-halos: words [0,12) and [172,184) of each row
    for (int z = tid; z < WHR * 24; z += 256) {
        int r = z / 24, u = z % 24;
        X[r][u < 12 ? u : 160 + u] = 0.f;
    }
    // stage interior: 640 float4 tasks, row-contiguous (coalesced)
#pragma unroll
    for (int it = 0; it < 3; ++it) {
        int task = it * 256 + tid;
        if (task < WHR * 40) {
            int q = task % 40, r = task / 40;
            float4 f = *(const float4*)(base + r * NV + 4 * q);
            X[r][12 + 4 * q]     = f.x;
            X[r][12 + 4 * q + 1] = f.y;
            X[r][12 + 4 * q + 2] = f.z;
            X[r][12 + 4 * q + 3] = f.w;
        }
    }
    __syncthreads();

    int c = tid & 15;              // w-chunk (lanes tile the row)
    int r = tid >> 4;              // h row
    float acc[OPT];
#pragma unroll
    for (int j = 0; j < OPT; ++j) acc[j] = 0.f;
#pragma unroll
    for (int it = 0; it < WIN; ++it) {
        float v = X[r][c * OPT + it];
#pragma unroll
        for (int j = 0; j < OPT; ++j) {
            int t = it - j;
            if (t >= 0 && t < KS) acc[j] = fmaf(g[t], v, acc[j]);
        }
    }
    __half* ob = out + (size_t)cd * PLANE + (size_t)(h0 + r) * NV + c * OPT;
#pragma unroll
    for (int j = 0; j < OPT / 2; ++j)
        *(__half2*)(ob + 2 * j) =
            __float22half2_rn(make_float2(acc[2 * j], acc[2 * j + 1]));
}

// ---------------- H pass: f16 in -> f16 out (r11, full-w tile) ----------------
__global__ __launch_bounds__(320) void conv_h(const __half* __restrict__ in,
                                              __half* __restrict__ out,
                                              const float* __restrict__ k3) {
    __shared__ __half2 T[TR][TP2];           // 104*84*4 = 34944 B
    float gs[KS];
    load_g(k3, gs);
    float2 g2[KS];
#pragma unroll
    for (int t = 0; t < KS; ++t) g2[t] = make_float2(gs[t], gs[t]);

    int tid = threadIdx.x;
    int b   = blockIdx.x;
    int hh  = b & 1;
    int cd  = b >> 1;              // c*160 + d
    int h0  = hh * HC2;
    const __half* base = in + (size_t)cd * PLANE;

#pragma unroll
    for (int it = 0; it < 7; ++it) {
        int task = it * 320 + tid;
        if (task < NTASK) {
            int r = task / 20, k = task % 20;
            int hg = h0 - RAD + r;
            uint4 v = make_uint4(0u, 0u, 0u, 0u);
            if (hg >= 0 && hg < NV)
                v = *(const uint4*)(base + hg * NV + 8 * k);
            *(uint4*)(&T[r][4 * k]) = v;
        }
    }
    __syncthreads();

    int wp = tid % 80, oc = tid / 80;        // wp 0..79, oc 0..3
#pragma unroll
    for (int hv = 0; hv < 2; ++hv) {
        int rb = (oc + 4 * hv) * OPT;        // 0..70
        float2 acc[OPT];
#pragma unroll
        for (int j = 0; j < OPT; ++j) acc[j] = make_float2(0.f, 0.f);
#pragma unroll
        for (int it = 0; it < WIN; ++it) {
            float2 v = __half22float2(T[rb + it][wp]);
#pragma unroll
            for (int j = 0; j < OPT; ++j) {
                int t = it - j;
                if (t >= 0 && t < KS) pk(acc[j], g2[t], v);
            }
        }
        __half* op = out + (size_t)cd * PLANE + (size_t)(h0 + rb) * NV + 2 * wp;
#pragma unroll
        for (int j = 0; j < OPT; ++j)
            *(__half2*)(op + j * NV) = __float22half2_rn(acc[j]);
    }
}

// ---------------- D pass: f16 in -> f32 out (r11, full-w tile) ----------------
__global__ __launch_bounds__(320) void conv_d(const __half* __restrict__ in,
                                              float* __restrict__ out,
                                              const float* __restrict__ k3) {
    __shared__ __half2 T[TR][TP2];           // 34944 B
    float gs[KS];
    load_g(k3, gs);
    float2 g2[KS];
#pragma unroll
    for (int t = 0; t < KS; ++t) g2[t] = make_float2(gs[t], gs[t]);

    int tid = threadIdx.x;
    int b   = blockIdx.x;
    int dh  = b & 1;
    int ch  = b >> 1;              // c*160 + h
    int c   = ch / NV, h = ch % NV;
    int d0  = dh * HC2;
    const __half* base = in + (size_t)c * VOL + h * NV;

#pragma unroll
    for (int it = 0; it < 7; ++it) {
        int task = it * 320 + tid;
        if (task < NTASK) {
            int r = task / 20, k = task % 20;
            int dg = d0 - RAD + r;
            uint4 v = make_uint4(0u, 0u, 0u, 0u);
            if (dg >= 0 && dg < NV)
                v = *(const uint4*)(base + (size_t)dg * PLANE + 8 * k);
            *(uint4*)(&T[r][4 * k]) = v;
        }
    }
    __syncthreads();

    int wp = tid % 80, oc = tid / 80;
#pragma unroll
    for (int hv = 0; hv < 2; ++hv) {
        int rb = (oc + 4 * hv) * OPT;        // 0..70
        float2 acc[OPT];
#pragma unroll
        for (int j = 0; j < OPT; ++j) acc[j] = make_float2(0.f, 0.f);
#pragma unroll
        for (int it = 0; it < WIN; ++it) {
            float2 v = __half22float2(T[rb + it][wp]);
#pragma unroll
            for (int j = 0; j < OPT; ++j) {
                int t = it - j;
                if (t >= 0 && t < KS) pk(acc[j], g2[t], v);
            }
        }
        float* op = out + (size_t)c * VOL + h * NV + 2 * wp;
#pragma unroll
        for (int j = 0; j < OPT; ++j)
            *(float2*)(op + (size_t)(d0 + rb + j) * PLANE) = acc[j];
    }
}

// Fallback (only if ws too small): direct 25^3-tap depthwise conv.
__global__ __launch_bounds__(256) void conv3d_direct(const float* __restrict__ x,
                                                     const float* __restrict__ k3,
                                                     float* __restrict__ out) {
    int idx = blockIdx.x * 256 + threadIdx.x;
    if (idx >= TOT) return;
    int w = idx % NV;
    int t = idx / NV;
    int h = t % NV; t /= NV;
    int d = t % NV;
    int c = t / NV;
    const float* kc = k3 + c * (KS * KS * KS);
    float acc = 0.f;
    for (int i = 0; i < KS; ++i) {
        int dd = d + i - RAD;
        if (dd < 0 || dd >= NV) continue;
        for (int j = 0; j < KS; ++j) {
            int hh = h + j - RAD;
            if (hh < 0 || hh >= NV) continue;
            const float* xr = x + (c * NV + dd) * NV * NV + hh * NV + (w - RAD);
            const float* kr = kc + (i * KS + j) * KS;
            int k0 = (RAD - w) > 0 ? (RAD - w) : 0;
            int k1 = (NV + RAD - w) < KS ? (NV + RAD - w) : KS;
            for (int k = k0; k < k1; ++k) acc += kr[k] * xr[k];
        }
    }
    out[idx] = acc;
}

extern "C" void kernel_launch(void* const* d_in, const int* in_sizes, int n_in,
                              void* d_out, int out_size, void* d_ws, size_t ws_size,
                              hipStream_t stream) {
    const float* x  = (const float*)d_in[0];
    const float* k3 = (const float*)d_in[1];
    float* out = (float*)d_out;

    if (ws_size >= (size_t)TOT * 2 * sizeof(__half)) {
        __half* tmpA = (__half*)d_ws;
        __half* tmpB = tmpA + TOT;
        conv_w<<<480 * 10, 256, 0, stream>>>(x, tmpA, k3);    // f32 -> f16 (W)
        conv_h<<<480 * 2, 320, 0, stream>>>(tmpA, tmpB, k3);  // f16 -> f16 (H)
        conv_d<<<480 * 2, 320, 0, stream>>>(tmpB, out, k3);   // f16 -> f32 (D)
    } else {
        conv3d_direct<<<(TOT + 255) / 256, 256, 0, stream>>>(x, k3, out);
    }
}